// Round 4
// baseline (269.007 us; speedup 1.0000x reference)
//
#include <hip/hip_runtime.h>

// GraphSAGE 2-layer: logits = meanAgg(relu(meanAgg(x@W1)) @ W2)
// N=100000, E=1600000, D_IN=128, D_H=128, D_OUT=64, fp32 in/out.
//
// R2: parallel scan. R3: agg x4 unroll. R4: FAILED 1024-thr gemm (spills).
// R5: gemm W from global. R6: counting-sort CSR build (no global atomics).
// R7: bf16 gather buffers, x8 unroll. R8: parallel HT scan.
// R9: MFMA gemms; k_prep transposes W to bf16 [n][k]; agg1 emits bf16.
// R10: wide dwordx4 gathers in agg (4 or 8 neighbors per load instr).
// R11: FAILED: shfl inside divergent branch (inactive-lane reads = 0).
// R12: shfl hoisted wave-uniform; 8% only — avg d=17 means the 16-wide
//      main loop ran ONCE and the 4-wide tail serialized the rest.
// R13: flat unrolled gather tiers. d is wave-uniform -> `if (nd>16)` is
//      divergence-free; slots fully unrolled + predicated, so a typical
//      row issues all ~8 gathers back-to-back (no loop-carried control,
//      max MLP), then unpacks. Tiers of 4 slots (agg1) / 2 slots (agg2)
//      avoid dead unpack work. Rare d>64 fallback loop kept.

#define DIN 128
#define DH 128
#define DOUT 64

#define BSH 9                    // 512 rows per bucket
#define COLB 17                  // col fits 17 bits (N=100000 < 2^17)
#define COLM ((1 << COLB) - 1)
#define LRM ((1 << BSH) - 1)
#define CHUNK 4096               // edges per hist/part block
#define CH_PT 16                 // edges per thread

typedef __attribute__((ext_vector_type(8))) short short8;
typedef __attribute__((ext_vector_type(4))) float floatx4;

__device__ __forceinline__ unsigned bfpack(float a, float b) {
    unsigned ua = __float_as_uint(a);
    unsigned ub = __float_as_uint(b);
    ua += 0x7fffu + ((ua >> 16) & 1u);
    ub += 0x7fffu + ((ub >> 16) & 1u);
    return (ua >> 16) | (ub & 0xffff0000u);
}
__device__ __forceinline__ unsigned short bf1(float a) {
    unsigned u = __float_as_uint(a);
    u += 0x7fffu + ((u >> 16) & 1u);
    return (unsigned short)(u >> 16);
}

// unpack a dwordx4 of 8 bf16 and accumulate into 8 fp32
__device__ __forceinline__ void acc8(float* a, uint4 v) {
    a[0] += __uint_as_float(v.x << 16);
    a[1] += __uint_as_float(v.x & 0xffff0000u);
    a[2] += __uint_as_float(v.y << 16);
    a[3] += __uint_as_float(v.y & 0xffff0000u);
    a[4] += __uint_as_float(v.z << 16);
    a[5] += __uint_as_float(v.z & 0xffff0000u);
    a[6] += __uint_as_float(v.w << 16);
    a[7] += __uint_as_float(v.w & 0xffff0000u);
}

// ---------------- weight prep: fp32 [k][n] -> bf16 [n][k] ----------------
__global__ __launch_bounds__(256) void k_prep(const float* __restrict__ W1,
                                              const float* __restrict__ W2,
                                              unsigned short* __restrict__ Wt1,
                                              unsigned short* __restrict__ Wt2) {
    int idx = blockIdx.x * 256 + threadIdx.x;
    if (idx < 128 * 128) {
        int k = idx >> 7, nn = idx & 127;
        Wt1[nn * 128 + k] = bf1(W1[idx]);
    }
    int i2 = idx - 128 * 128;
    if (i2 >= 0 && i2 < 128 * 64) {
        int k = i2 >> 6, nn = i2 & 63;
        Wt2[nn * 128 + k] = bf1(W2[i2]);
    }
}

// ---------------- CSR build (counting sort) ----------------

__global__ __launch_bounds__(256) void k_hist(const int* __restrict__ row,
                                              int* __restrict__ HT,
                                              int E, int nb, int nch) {
    __shared__ int h[512];
    int t = threadIdx.x, c = blockIdx.x;
    for (int i = t; i < nb; i += 256) h[i] = 0;
    __syncthreads();
    int base = c * CHUNK;
#pragma unroll
    for (int i = 0; i < CH_PT; ++i) {
        int e = base + i * 256 + t;
        if (e < E) atomicAdd(&h[row[e] >> BSH], 1);
    }
    __syncthreads();
    for (int i = t; i < nb; i += 256) HT[(size_t)i * nch + c] = h[i];
}

__global__ __launch_bounds__(256) void k_hscan_row(int* __restrict__ HT,
                                                   int* __restrict__ bsum,
                                                   int nch) {
    __shared__ int sh[256];
    int b = blockIdx.x, t = threadIdx.x;
    int carry = 0;
    for (int tile = 0; tile < nch; tile += 256) {
        int idx = tile + t;
        int v = (idx < nch) ? HT[(size_t)b * nch + idx] : 0;
        sh[t] = v;
        __syncthreads();
        for (int d = 1; d < 256; d <<= 1) {
            int u = (t >= d) ? sh[t - d] : 0;
            __syncthreads();
            sh[t] += u;
            __syncthreads();
        }
        if (idx < nch) HT[(size_t)b * nch + idx] = carry + sh[t] - v;
        carry += sh[255];
        __syncthreads();
    }
    if (t == 0) bsum[b] = carry;
}

__global__ __launch_bounds__(256) void k_hscan_base(const int* __restrict__ bsum,
                                                    int* __restrict__ bucketBase,
                                                    int nb, int E) {
    __shared__ int sh[256];
    int t = threadIdx.x;
    int v = (t < nb) ? bsum[t] : 0;
    sh[t] = v;
    __syncthreads();
    for (int d = 1; d < 256; d <<= 1) {
        int u = (t >= d) ? sh[t - d] : 0;
        __syncthreads();
        sh[t] += u;
        __syncthreads();
    }
    if (t < nb) bucketBase[t] = sh[t] - v;
    if (t == 0) bucketBase[nb] = E;
}

__global__ __launch_bounds__(256) void k_part(const int* __restrict__ row,
                                              const int* __restrict__ col,
                                              const int* __restrict__ HT,
                                              const int* __restrict__ bucketBase,
                                              int* __restrict__ packed,
                                              int E, int nb, int nch) {
    __shared__ int cur[512];
    int t = threadIdx.x, c = blockIdx.x;
    for (int i = t; i < nb; i += 256)
        cur[i] = HT[(size_t)i * nch + c] + bucketBase[i];
    __syncthreads();
    int base = c * CHUNK;
#pragma unroll
    for (int i = 0; i < CH_PT; ++i) {
        int e = base + i * 256 + t;
        if (e < E) {
            int r = row[e], cc = col[e];
            int b = r >> BSH;
            int pos = atomicAdd(&cur[b], 1);
            packed[pos] = ((r & LRM) << COLB) | cc;
        }
    }
}

__global__ __launch_bounds__(256) void k_build(const int* __restrict__ packed,
                                               const int* __restrict__ bucketBase,
                                               int* __restrict__ csr,
                                               int* __restrict__ offs,
                                               int* __restrict__ degc,
                                               float* __restrict__ invdeg,
                                               int N, int nb) {
    __shared__ int hist[512], scn[512], part[256];
    int t = threadIdx.x, b = blockIdx.x;
    int lo = bucketBase[b], hi = bucketBase[b + 1];
    int base_row = b << BSH;
    int nloc = N - base_row; if (nloc > 512) nloc = 512;
    hist[t] = 0; hist[t + 256] = 0;
    __syncthreads();
    for (int e = lo + t; e < hi; e += 256)
        atomicAdd(&hist[packed[e] >> COLB], 1);
    __syncthreads();
    int a = hist[2 * t], b2 = hist[2 * t + 1];
    part[t] = a + b2;
    __syncthreads();
    for (int d = 1; d < 256; d <<= 1) {
        int v = (t >= d) ? part[t - d] : 0;
        __syncthreads();
        part[t] += v;
        __syncthreads();
    }
    int bp = (t == 0) ? 0 : part[t - 1];
    scn[2 * t] = bp;
    scn[2 * t + 1] = bp + a;
    __syncthreads();
    for (int i = t; i < nloc; i += 256) {
        int r = base_row + i;
        offs[r] = lo + scn[i];
        int d = hist[i];
        degc[r] = d;
        invdeg[r] = 1.0f / (float)d;
    }
    __syncthreads();
    for (int e = lo + t; e < hi; e += 256) {
        int p = packed[e];
        int pos = lo + atomicAdd(&scn[p >> COLB], 1);
        csr[pos] = p & COLM;
    }
}

// ---------------- MFMA GEMMs ----------------

// h1b[n,128](bf16) = X @ W1. 256 thr, 64-row block; wave w: rows w*16..+15.
__global__ __launch_bounds__(256) void k_gemm1(const float* __restrict__ X,
                                               const unsigned short* __restrict__ Wt,
                                               unsigned short* __restrict__ H1b, int n) {
    __shared__ unsigned short xs[64][136];    // pitch 272B: 2-way-bank-safe b128
    __shared__ unsigned short wt[128][136];
    int tid = threadIdx.x;
    int r0 = blockIdx.x * 64;

    for (int i = tid; i < 64 * 32; i += 256) {
        int r = i >> 5, c4 = i & 31;
        float4 v = make_float4(0.f, 0.f, 0.f, 0.f);
        if (r0 + r < n) v = ((const float4*)X)[(size_t)(r0 + r) * 32 + c4];
        *(uint2*)&xs[r][c4 * 4] = make_uint2(bfpack(v.x, v.y), bfpack(v.z, v.w));
    }
    for (int i = tid; i < 128 * 16; i += 256) {
        int r = i >> 4, c = i & 15;
        *(uint4*)&wt[r][c * 8] = ((const uint4*)Wt)[r * 16 + c];
    }
    __syncthreads();

    int w = tid >> 6, lane = tid & 63;
    int ml = lane & 15, q = lane >> 4;
    floatx4 acc[8];
#pragma unroll
    for (int t = 0; t < 8; ++t) acc[t] = (floatx4)(0.f);

#pragma unroll
    for (int kc = 0; kc < 4; ++kc) {
        short8 af = *(const short8*)&xs[w * 16 + ml][kc * 32 + q * 8];
#pragma unroll
        for (int nt = 0; nt < 8; ++nt) {
            short8 bf = *(const short8*)&wt[nt * 16 + ml][kc * 32 + q * 8];
            acc[nt] = __builtin_amdgcn_mfma_f32_16x16x32_bf16(af, bf, acc[nt], 0, 0, 0);
        }
    }
#pragma unroll
    for (int nt = 0; nt < 8; ++nt)
#pragma unroll
        for (int r = 0; r < 4; ++r) {
            int rr = r0 + w * 16 + q * 4 + r;
            if (rr < n)
                H1b[(size_t)rr * 128 + nt * 16 + ml] = bf1(acc[nt][r]);
        }
}

// h2b[n,64](bf16) = h(bf16) @ W2. Same structure, N=64.
__global__ __launch_bounds__(256) void k_gemm2(const unsigned* __restrict__ Hin,
                                               const unsigned short* __restrict__ Wt,
                                               unsigned short* __restrict__ H2b, int n) {
    __shared__ unsigned short xs[64][136];
    __shared__ unsigned short wt[64][136];
    int tid = threadIdx.x;
    int r0 = blockIdx.x * 64;

    for (int i = tid; i < 64 * 16; i += 256) {
        int r = i >> 4, c = i & 15;
        uint4 v = make_uint4(0u, 0u, 0u, 0u);
        if (r0 + r < n) v = ((const uint4*)Hin)[(size_t)(r0 + r) * 16 + c];
        *(uint4*)&xs[r][c * 8] = v;
    }
    for (int i = tid; i < 64 * 16; i += 256) {
        int r = i >> 4, c = i & 15;
        *(uint4*)&wt[r][c * 8] = ((const uint4*)Wt)[r * 16 + c];
    }
    __syncthreads();

    int w = tid >> 6, lane = tid & 63;
    int ml = lane & 15, q = lane >> 4;
    floatx4 acc[4];
#pragma unroll
    for (int t = 0; t < 4; ++t) acc[t] = (floatx4)(0.f);

#pragma unroll
    for (int kc = 0; kc < 4; ++kc) {
        short8 af = *(const short8*)&xs[w * 16 + ml][kc * 32 + q * 8];
#pragma unroll
        for (int nt = 0; nt < 4; ++nt) {
            short8 bf = *(const short8*)&wt[nt * 16 + ml][kc * 32 + q * 8];
            acc[nt] = __builtin_amdgcn_mfma_f32_16x16x32_bf16(af, bf, acc[nt], 0, 0, 0);
        }
    }
#pragma unroll
    for (int nt = 0; nt < 4; ++nt)
#pragma unroll
        for (int r = 0; r < 4; ++r) {
            int rr = r0 + w * 16 + q * 4 + r;
            if (rr < n)
                H2b[(size_t)rr * 64 + nt * 16 + ml] = bf1(acc[nt][r]);
        }
}

// ---------------- Aggregations ----------------

// agg1: h[row](bf16) = relu((1/deg) * sum h1b[c]), D=128 (row = 16 uint4).
// One row per wave; csr row cached in regs (one coalesced load), indices
// distributed via wave-uniform shfl. Gathers fully unrolled in tiers of 4
// slots (16 neighbors); d is wave-uniform so tier branches don't diverge.
// All gathers of a tier issue back-to-back before unpack (max MLP).
#define A1_SLOT(vv, s)                                                      \
    {                                                                       \
        int j = (s) * 4 + g;                                                \
        int c = __shfl(idx, (j < nd) ? j : 0);                              \
        vv = make_uint4(0u, 0u, 0u, 0u);                                    \
        if (j < nd) vv = H1b[((unsigned)c << 4) + sl];                      \
    }

__global__ __launch_bounds__(256) void k_agg1(const uint4* __restrict__ H1b,
                                              const int* __restrict__ offs,
                                              const int* __restrict__ degc,
                                              const float* __restrict__ invdeg,
                                              const int* __restrict__ csr,
                                              uint4* __restrict__ Hout, int n) {
    int wave = threadIdx.x >> 6, lane = threadIdx.x & 63;
    int row = blockIdx.x * 4 + wave;
    if (row >= n) return;
    int start = offs[row], d = degc[row];
    float inv = invdeg[row];
    int g = lane >> 4;       // neighbor slot 0..3
    int sl = lane & 15;      // 16B segment within row

    int nd = d < 64 ? d : 64;
    int idx = (lane < nd) ? csr[start + lane] : 0;

    float acc[8];
#pragma unroll
    for (int k = 0; k < 8; ++k) acc[k] = 0.f;

    uint4 v0, v1, v2, v3;
    A1_SLOT(v0, 0) A1_SLOT(v1, 1) A1_SLOT(v2, 2) A1_SLOT(v3, 3)
    acc8(acc, v0); acc8(acc, v1); acc8(acc, v2); acc8(acc, v3);
    if (nd > 16) {
        A1_SLOT(v0, 4) A1_SLOT(v1, 5) A1_SLOT(v2, 6) A1_SLOT(v3, 7)
        acc8(acc, v0); acc8(acc, v1); acc8(acc, v2); acc8(acc, v3);
    }
    if (nd > 32) {
        A1_SLOT(v0, 8) A1_SLOT(v1, 9) A1_SLOT(v2, 10) A1_SLOT(v3, 11)
        acc8(acc, v0); acc8(acc, v1); acc8(acc, v2); acc8(acc, v3);
    }
    if (nd > 48) {
        A1_SLOT(v0, 12) A1_SLOT(v1, 13) A1_SLOT(v2, 14) A1_SLOT(v3, 15)
        acc8(acc, v0); acc8(acc, v1); acc8(acc, v2); acc8(acc, v3);
    }
    if (d > 64) {                    // rare fallback
        for (int i = 64; i < d; i += 4) {
            int j = i + g;
            uint4 v = make_uint4(0u, 0u, 0u, 0u);
            if (j < d) {
                int c = csr[start + j];
                v = H1b[((unsigned)c << 4) + sl];
            }
            acc8(acc, v);
        }
    }

#pragma unroll
    for (int k = 0; k < 8; ++k) {
        acc[k] += __shfl_xor(acc[k], 16);
        acc[k] += __shfl_xor(acc[k], 32);
    }

    if (g == 0) {
#pragma unroll
        for (int k = 0; k < 8; ++k) acc[k] = fmaxf(acc[k] * inv, 0.f);
        uint4 o;
        o.x = bfpack(acc[0], acc[1]);
        o.y = bfpack(acc[2], acc[3]);
        o.z = bfpack(acc[4], acc[5]);
        o.w = bfpack(acc[6], acc[7]);
        Hout[(size_t)row * 16 + sl] = o;
    }
}

// agg2: Out[row](fp32) = (1/deg) * sum h2b[c], D=64 (row = 8 uint4).
// Same scheme; 8-lane groups -> 8 neighbors per slot, tiers of 2 slots.
#define A2_SLOT(vv, s)                                                      \
    {                                                                       \
        int j = (s) * 8 + g;                                                \
        int c = __shfl(idx, (j < nd) ? j : 0);                              \
        vv = make_uint4(0u, 0u, 0u, 0u);                                    \
        if (j < nd) vv = H2b[((unsigned)c << 3) + sl];                      \
    }

__global__ __launch_bounds__(256) void k_agg2(const uint4* __restrict__ H2b,
                                              const int* __restrict__ offs,
                                              const int* __restrict__ degc,
                                              const float* __restrict__ invdeg,
                                              const int* __restrict__ csr,
                                              float* __restrict__ Out, int n) {
    int wave = threadIdx.x >> 6, lane = threadIdx.x & 63;
    int row = blockIdx.x * 4 + wave;
    if (row >= n) return;
    int start = offs[row], d = degc[row];
    float inv = invdeg[row];
    int g = lane >> 3;       // neighbor slot 0..7
    int sl = lane & 7;       // 16B segment within row

    int nd = d < 64 ? d : 64;
    int idx = (lane < nd) ? csr[start + lane] : 0;

    float acc[8];
#pragma unroll
    for (int k = 0; k < 8; ++k) acc[k] = 0.f;

    uint4 v0, v1;
    A2_SLOT(v0, 0) A2_SLOT(v1, 1)
    acc8(acc, v0); acc8(acc, v1);
    if (nd > 16) {
        A2_SLOT(v0, 2) A2_SLOT(v1, 3)
        acc8(acc, v0); acc8(acc, v1);
    }
    if (nd > 32) {
        A2_SLOT(v0, 4) A2_SLOT(v1, 5)
        acc8(acc, v0); acc8(acc, v1);
    }
    if (nd > 48) {
        A2_SLOT(v0, 6) A2_SLOT(v1, 7)
        acc8(acc, v0); acc8(acc, v1);
    }
    if (d > 64) {                    // rare fallback
        for (int i = 64; i < d; i += 8) {
            int j = i + g;
            uint4 v = make_uint4(0u, 0u, 0u, 0u);
            if (j < d) {
                int c = csr[start + j];
                v = H2b[((unsigned)c << 3) + sl];
            }
            acc8(acc, v);
        }
    }

#pragma unroll
    for (int k = 0; k < 8; ++k) {
        acc[k] += __shfl_xor(acc[k], 8);
        acc[k] += __shfl_xor(acc[k], 16);
        acc[k] += __shfl_xor(acc[k], 32);
    }

    if (g == 0) {
        float4 o0, o1;
        o0.x = acc[0] * inv; o0.y = acc[1] * inv;
        o0.z = acc[2] * inv; o0.w = acc[3] * inv;
        o1.x = acc[4] * inv; o1.y = acc[5] * inv;
        o1.z = acc[6] * inv; o1.w = acc[7] * inv;
        ((float4*)Out)[(size_t)row * 16 + sl * 2]     = o0;
        ((float4*)Out)[(size_t)row * 16 + sl * 2 + 1] = o1;
    }
}

extern "C" void kernel_launch(void* const* d_in, const int* in_sizes, int n_in,
                              void* d_out, int out_size, void* d_ws, size_t ws_size,
                              hipStream_t stream) {
    const float* x    = (const float*)d_in[0];
    const float* W1   = (const float*)d_in[1];
    const float* W2   = (const float*)d_in[2];
    const int*   erow = (const int*)d_in[3];
    const int*   ecol = (const int*)d_in[4];
    const int N = in_sizes[0] / DIN;
    const int E = in_sizes[3];

    const int nb  = (N + (1 << BSH) - 1) >> BSH;   // 196 buckets
    const int nch = (E + CHUNK - 1) / CHUNK;       // 391 chunks

    size_t o = 0;
    auto take = [&](size_t nbytes) {
        void* p = (char*)d_ws + o;
        o += (nbytes + 255) & ~(size_t)255;
        return p;
    };
    int*            HT     = (int*)take((size_t)nb * nch * 4);
    int*            bsum   = (int*)take((size_t)nb * 4);
    int*            bbase  = (int*)take((size_t)(nb + 1) * 4);
    int*            packed = (int*)take((size_t)E * 4);
    int*            csr    = (int*)take((size_t)E * 4);
    int*            offs   = (int*)take((size_t)N * 4);
    int*            degc   = (int*)take((size_t)N * 4);
    float*          invdeg = (float*)take((size_t)N * 4);
    unsigned short* Wt1    = (unsigned short*)take(128 * 128 * 2);
    unsigned short* Wt2    = (unsigned short*)take(64 * 128 * 2);
    unsigned*       h1b    = (unsigned*)take((size_t)N * DH * 2);   // bf16
    unsigned*       h      = (unsigned*)take((size_t)N * DH * 2);   // bf16
    unsigned*       h2b    = h1b;   // reuses h1b (dead after agg1)

    k_prep      <<<96,  256, 0, stream>>>(W1, W2, Wt1, Wt2);
    k_hist      <<<nch, 256, 0, stream>>>(erow, HT, E, nb, nch);
    k_hscan_row <<<nb,  256, 0, stream>>>(HT, bsum, nch);
    k_hscan_base<<<1,   256, 0, stream>>>(bsum, bbase, nb, E);
    k_part      <<<nch, 256, 0, stream>>>(erow, ecol, HT, bbase, packed, E, nb, nch);
    k_build     <<<nb,  256, 0, stream>>>(packed, bbase, csr, offs, degc, invdeg, N, nb);
    k_gemm1<<<(N + 63) / 64, 256, 0, stream>>>(x, Wt1, (unsigned short*)h1b, N);
    k_agg1 <<<(N + 3) / 4, 256, 0, stream>>>((const uint4*)h1b, offs, degc, invdeg,
                                             csr, (uint4*)h, N);
    k_gemm2<<<(N + 63) / 64, 256, 0, stream>>>(h, Wt2, (unsigned short*)h2b, N);
    k_agg2 <<<(N + 3) / 4, 256, 0, stream>>>((const uint4*)h2b, offs, degc,
                                             invdeg, csr, (float*)d_out, N);
}

// Round 5
// 266.479 us; speedup vs baseline: 1.0095x; 1.0095x over previous
//
#include <hip/hip_runtime.h>

// GraphSAGE 2-layer: logits = meanAgg(relu(meanAgg(x@W1)) @ W2)
// N=100000, E=1600000, D_IN=128, D_H=128, D_OUT=64, fp32 in/out.
//
// R2: parallel scan. R3: agg x4 unroll. R4: FAILED 1024-thr gemm (spills).
// R5: gemm W from global. R6: counting-sort CSR build (no global atomics).
// R7: bf16 gather buffers, x8 unroll. R8: parallel HT scan.
// R9: MFMA gemms; k_prep transposes W to bf16 [n][k]; agg1 emits bf16.
// R10: wide dwordx4 gathers in agg (4 or 8 neighbors per load instr).
// R11: FAILED: shfl inside divergent branch (inactive-lane reads = 0).
// R12: shfl hoisted wave-uniform. R13: flat unrolled gather tiers —
//      NEUTRAL: miss traffic pinned at 181MB/3.17TB/s; latency-MLP was
//      not the limit; bytes are.
// R14: h1b in fp8 e4m3 (HW cvt_pk): 128B rows. Working set 25.6->12.8MB
//      (better L2 hit), miss bytes and line count halve, unpack VALU
//      ~halves (cvt_pk = 2 elems/inst). gemm1 epilogue encodes fp8;
//      agg1 gathers fp8, 8 lanes/row -> 8 neighbors per dwordx4.
//      h (agg1 out) stays bf16; agg2/gemm2 untouched.

#define DIN 128
#define DH 128
#define DOUT 64

#define BSH 9                    // 512 rows per bucket
#define COLB 17                  // col fits 17 bits (N=100000 < 2^17)
#define COLM ((1 << COLB) - 1)
#define LRM ((1 << BSH) - 1)
#define CHUNK 4096               // edges per hist/part block
#define CH_PT 16                 // edges per thread

typedef __attribute__((ext_vector_type(8))) short short8;
typedef __attribute__((ext_vector_type(4))) float floatx4;
typedef __attribute__((ext_vector_type(2))) float fx2;

__device__ __forceinline__ unsigned bfpack(float a, float b) {
    unsigned ua = __float_as_uint(a);
    unsigned ub = __float_as_uint(b);
    ua += 0x7fffu + ((ua >> 16) & 1u);
    ub += 0x7fffu + ((ub >> 16) & 1u);
    return (ua >> 16) | (ub & 0xffff0000u);
}
__device__ __forceinline__ unsigned short bf1(float a) {
    unsigned u = __float_as_uint(a);
    u += 0x7fffu + ((u >> 16) & 1u);
    return (unsigned short)(u >> 16);
}
// fp8 e4m3 encode (1 byte) via HW packed convert
__device__ __forceinline__ unsigned char f8enc(float v) {
    return (unsigned char)(__builtin_amdgcn_cvt_pk_fp8_f32(v, v, 0, false) & 0xff);
}

// unpack a dwordx4 of 8 bf16 and accumulate into 8 fp32
__device__ __forceinline__ void acc8(float* a, uint4 v) {
    a[0] += __uint_as_float(v.x << 16);
    a[1] += __uint_as_float(v.x & 0xffff0000u);
    a[2] += __uint_as_float(v.y << 16);
    a[3] += __uint_as_float(v.y & 0xffff0000u);
    a[4] += __uint_as_float(v.z << 16);
    a[5] += __uint_as_float(v.z & 0xffff0000u);
    a[6] += __uint_as_float(v.w << 16);
    a[7] += __uint_as_float(v.w & 0xffff0000u);
}

// unpack a dwordx4 of 16 fp8 and accumulate into 16 fp32 (HW cvt: 2/inst)
__device__ __forceinline__ void accf8(float* a, uint4 v) {
    fx2 p;
    p = __builtin_amdgcn_cvt_pk_f32_fp8((int)v.x, false); a[0]  += p.x; a[1]  += p.y;
    p = __builtin_amdgcn_cvt_pk_f32_fp8((int)v.x, true);  a[2]  += p.x; a[3]  += p.y;
    p = __builtin_amdgcn_cvt_pk_f32_fp8((int)v.y, false); a[4]  += p.x; a[5]  += p.y;
    p = __builtin_amdgcn_cvt_pk_f32_fp8((int)v.y, true);  a[6]  += p.x; a[7]  += p.y;
    p = __builtin_amdgcn_cvt_pk_f32_fp8((int)v.z, false); a[8]  += p.x; a[9]  += p.y;
    p = __builtin_amdgcn_cvt_pk_f32_fp8((int)v.z, true);  a[10] += p.x; a[11] += p.y;
    p = __builtin_amdgcn_cvt_pk_f32_fp8((int)v.w, false); a[12] += p.x; a[13] += p.y;
    p = __builtin_amdgcn_cvt_pk_f32_fp8((int)v.w, true);  a[14] += p.x; a[15] += p.y;
}

// ---------------- weight prep: fp32 [k][n] -> bf16 [n][k] ----------------
__global__ __launch_bounds__(256) void k_prep(const float* __restrict__ W1,
                                              const float* __restrict__ W2,
                                              unsigned short* __restrict__ Wt1,
                                              unsigned short* __restrict__ Wt2) {
    int idx = blockIdx.x * 256 + threadIdx.x;
    if (idx < 128 * 128) {
        int k = idx >> 7, nn = idx & 127;
        Wt1[nn * 128 + k] = bf1(W1[idx]);
    }
    int i2 = idx - 128 * 128;
    if (i2 >= 0 && i2 < 128 * 64) {
        int k = i2 >> 6, nn = i2 & 63;
        Wt2[nn * 128 + k] = bf1(W2[i2]);
    }
}

// ---------------- CSR build (counting sort) ----------------

__global__ __launch_bounds__(256) void k_hist(const int* __restrict__ row,
                                              int* __restrict__ HT,
                                              int E, int nb, int nch) {
    __shared__ int h[512];
    int t = threadIdx.x, c = blockIdx.x;
    for (int i = t; i < nb; i += 256) h[i] = 0;
    __syncthreads();
    int base = c * CHUNK;
#pragma unroll
    for (int i = 0; i < CH_PT; ++i) {
        int e = base + i * 256 + t;
        if (e < E) atomicAdd(&h[row[e] >> BSH], 1);
    }
    __syncthreads();
    for (int i = t; i < nb; i += 256) HT[(size_t)i * nch + c] = h[i];
}

__global__ __launch_bounds__(256) void k_hscan_row(int* __restrict__ HT,
                                                   int* __restrict__ bsum,
                                                   int nch) {
    __shared__ int sh[256];
    int b = blockIdx.x, t = threadIdx.x;
    int carry = 0;
    for (int tile = 0; tile < nch; tile += 256) {
        int idx = tile + t;
        int v = (idx < nch) ? HT[(size_t)b * nch + idx] : 0;
        sh[t] = v;
        __syncthreads();
        for (int d = 1; d < 256; d <<= 1) {
            int u = (t >= d) ? sh[t - d] : 0;
            __syncthreads();
            sh[t] += u;
            __syncthreads();
        }
        if (idx < nch) HT[(size_t)b * nch + idx] = carry + sh[t] - v;
        carry += sh[255];
        __syncthreads();
    }
    if (t == 0) bsum[b] = carry;
}

__global__ __launch_bounds__(256) void k_hscan_base(const int* __restrict__ bsum,
                                                    int* __restrict__ bucketBase,
                                                    int nb, int E) {
    __shared__ int sh[256];
    int t = threadIdx.x;
    int v = (t < nb) ? bsum[t] : 0;
    sh[t] = v;
    __syncthreads();
    for (int d = 1; d < 256; d <<= 1) {
        int u = (t >= d) ? sh[t - d] : 0;
        __syncthreads();
        sh[t] += u;
        __syncthreads();
    }
    if (t < nb) bucketBase[t] = sh[t] - v;
    if (t == 0) bucketBase[nb] = E;
}

__global__ __launch_bounds__(256) void k_part(const int* __restrict__ row,
                                              const int* __restrict__ col,
                                              const int* __restrict__ HT,
                                              const int* __restrict__ bucketBase,
                                              int* __restrict__ packed,
                                              int E, int nb, int nch) {
    __shared__ int cur[512];
    int t = threadIdx.x, c = blockIdx.x;
    for (int i = t; i < nb; i += 256)
        cur[i] = HT[(size_t)i * nch + c] + bucketBase[i];
    __syncthreads();
    int base = c * CHUNK;
#pragma unroll
    for (int i = 0; i < CH_PT; ++i) {
        int e = base + i * 256 + t;
        if (e < E) {
            int r = row[e], cc = col[e];
            int b = r >> BSH;
            int pos = atomicAdd(&cur[b], 1);
            packed[pos] = ((r & LRM) << COLB) | cc;
        }
    }
}

__global__ __launch_bounds__(256) void k_build(const int* __restrict__ packed,
                                               const int* __restrict__ bucketBase,
                                               int* __restrict__ csr,
                                               int* __restrict__ offs,
                                               int* __restrict__ degc,
                                               float* __restrict__ invdeg,
                                               int N, int nb) {
    __shared__ int hist[512], scn[512], part[256];
    int t = threadIdx.x, b = blockIdx.x;
    int lo = bucketBase[b], hi = bucketBase[b + 1];
    int base_row = b << BSH;
    int nloc = N - base_row; if (nloc > 512) nloc = 512;
    hist[t] = 0; hist[t + 256] = 0;
    __syncthreads();
    for (int e = lo + t; e < hi; e += 256)
        atomicAdd(&hist[packed[e] >> COLB], 1);
    __syncthreads();
    int a = hist[2 * t], b2 = hist[2 * t + 1];
    part[t] = a + b2;
    __syncthreads();
    for (int d = 1; d < 256; d <<= 1) {
        int v = (t >= d) ? part[t - d] : 0;
        __syncthreads();
        part[t] += v;
        __syncthreads();
    }
    int bp = (t == 0) ? 0 : part[t - 1];
    scn[2 * t] = bp;
    scn[2 * t + 1] = bp + a;
    __syncthreads();
    for (int i = t; i < nloc; i += 256) {
        int r = base_row + i;
        offs[r] = lo + scn[i];
        int d = hist[i];
        degc[r] = d;
        invdeg[r] = 1.0f / (float)d;
    }
    __syncthreads();
    for (int e = lo + t; e < hi; e += 256) {
        int p = packed[e];
        int pos = lo + atomicAdd(&scn[p >> COLB], 1);
        csr[pos] = p & COLM;
    }
}

// ---------------- MFMA GEMMs ----------------

// h1f8[n,128](fp8 e4m3) = X @ W1. 256 thr, 64-row block.
__global__ __launch_bounds__(256) void k_gemm1(const float* __restrict__ X,
                                               const unsigned short* __restrict__ Wt,
                                               unsigned char* __restrict__ H1f8, int n) {
    __shared__ unsigned short xs[64][136];    // pitch 272B: 2-way-bank-safe b128
    __shared__ unsigned short wt[128][136];
    int tid = threadIdx.x;
    int r0 = blockIdx.x * 64;

    for (int i = tid; i < 64 * 32; i += 256) {
        int r = i >> 5, c4 = i & 31;
        float4 v = make_float4(0.f, 0.f, 0.f, 0.f);
        if (r0 + r < n) v = ((const float4*)X)[(size_t)(r0 + r) * 32 + c4];
        *(uint2*)&xs[r][c4 * 4] = make_uint2(bfpack(v.x, v.y), bfpack(v.z, v.w));
    }
    for (int i = tid; i < 128 * 16; i += 256) {
        int r = i >> 4, c = i & 15;
        *(uint4*)&wt[r][c * 8] = ((const uint4*)Wt)[r * 16 + c];
    }
    __syncthreads();

    int w = tid >> 6, lane = tid & 63;
    int ml = lane & 15, q = lane >> 4;
    floatx4 acc[8];
#pragma unroll
    for (int t = 0; t < 8; ++t) acc[t] = (floatx4)(0.f);

#pragma unroll
    for (int kc = 0; kc < 4; ++kc) {
        short8 af = *(const short8*)&xs[w * 16 + ml][kc * 32 + q * 8];
#pragma unroll
        for (int nt = 0; nt < 8; ++nt) {
            short8 bf = *(const short8*)&wt[nt * 16 + ml][kc * 32 + q * 8];
            acc[nt] = __builtin_amdgcn_mfma_f32_16x16x32_bf16(af, bf, acc[nt], 0, 0, 0);
        }
    }
#pragma unroll
    for (int nt = 0; nt < 8; ++nt)
#pragma unroll
        for (int r = 0; r < 4; ++r) {
            int rr = r0 + w * 16 + q * 4 + r;
            if (rr < n)
                H1f8[(size_t)rr * 128 + nt * 16 + ml] = f8enc(acc[nt][r]);
        }
}

// h2b[n,64](bf16) = h(bf16) @ W2. Same structure, N=64.
__global__ __launch_bounds__(256) void k_gemm2(const unsigned* __restrict__ Hin,
                                               const unsigned short* __restrict__ Wt,
                                               unsigned short* __restrict__ H2b, int n) {
    __shared__ unsigned short xs[64][136];
    __shared__ unsigned short wt[64][136];
    int tid = threadIdx.x;
    int r0 = blockIdx.x * 64;

    for (int i = tid; i < 64 * 16; i += 256) {
        int r = i >> 4, c = i & 15;
        uint4 v = make_uint4(0u, 0u, 0u, 0u);
        if (r0 + r < n) v = ((const uint4*)Hin)[(size_t)(r0 + r) * 16 + c];
        *(uint4*)&xs[r][c * 8] = v;
    }
    for (int i = tid; i < 64 * 16; i += 256) {
        int r = i >> 4, c = i & 15;
        *(uint4*)&wt[r][c * 8] = ((const uint4*)Wt)[r * 16 + c];
    }
    __syncthreads();

    int w = tid >> 6, lane = tid & 63;
    int ml = lane & 15, q = lane >> 4;
    floatx4 acc[4];
#pragma unroll
    for (int t = 0; t < 4; ++t) acc[t] = (floatx4)(0.f);

#pragma unroll
    for (int kc = 0; kc < 4; ++kc) {
        short8 af = *(const short8*)&xs[w * 16 + ml][kc * 32 + q * 8];
#pragma unroll
        for (int nt = 0; nt < 4; ++nt) {
            short8 bf = *(const short8*)&wt[nt * 16 + ml][kc * 32 + q * 8];
            acc[nt] = __builtin_amdgcn_mfma_f32_16x16x32_bf16(af, bf, acc[nt], 0, 0, 0);
        }
    }
#pragma unroll
    for (int nt = 0; nt < 4; ++nt)
#pragma unroll
        for (int r = 0; r < 4; ++r) {
            int rr = r0 + w * 16 + q * 4 + r;
            if (rr < n)
                H2b[(size_t)rr * 64 + nt * 16 + ml] = bf1(acc[nt][r]);
        }
}

// ---------------- Aggregations ----------------

// agg1: h[row](bf16) = relu((1/deg) * sum h1f8[c]), fp8 rows of 128B =
// 8 uint4. 8 lanes per neighbor row (sl = lane&7), g = lane>>3 -> 8
// neighbors per dwordx4 gather. Gathers unrolled in tiers of 2 slots
// (16 nbrs); d wave-uniform so tier branches don't diverge. Decode via
// HW v_cvt_pk_f32_fp8 (2 elems/inst); 16 f32 acc per lane.
#define AF_SLOT(vv, s)                                                      \
    {                                                                       \
        int j = (s) * 8 + g;                                                \
        int c = __shfl(idx, (j < nd) ? j : 0);                              \
        vv = make_uint4(0u, 0u, 0u, 0u);                                    \
        if (j < nd) vv = H1f8[((unsigned)c << 3) + sl];                     \
    }

__global__ __launch_bounds__(256) void k_agg1(const uint4* __restrict__ H1f8,
                                              const int* __restrict__ offs,
                                              const int* __restrict__ degc,
                                              const float* __restrict__ invdeg,
                                              const int* __restrict__ csr,
                                              uint4* __restrict__ Hout, int n) {
    int wave = threadIdx.x >> 6, lane = threadIdx.x & 63;
    int row = blockIdx.x * 4 + wave;
    if (row >= n) return;
    int start = offs[row], d = degc[row];
    float inv = invdeg[row];
    int g = lane >> 3;       // neighbor slot 0..7
    int sl = lane & 7;       // 16B segment within 128B fp8 row

    int nd = d < 64 ? d : 64;
    int idx = (lane < nd) ? csr[start + lane] : 0;

    float acc[16];
#pragma unroll
    for (int k = 0; k < 16; ++k) acc[k] = 0.f;

    uint4 v0, v1;
    AF_SLOT(v0, 0) AF_SLOT(v1, 1)
    accf8(acc, v0); accf8(acc, v1);
    if (nd > 16) {
        AF_SLOT(v0, 2) AF_SLOT(v1, 3)
        accf8(acc, v0); accf8(acc, v1);
    }
    if (nd > 32) {
        AF_SLOT(v0, 4) AF_SLOT(v1, 5)
        accf8(acc, v0); accf8(acc, v1);
    }
    if (nd > 48) {
        AF_SLOT(v0, 6) AF_SLOT(v1, 7)
        accf8(acc, v0); accf8(acc, v1);
    }
    if (d > 64) {                    // rare fallback
        for (int i = 64; i < d; i += 8) {
            int j = i + g;
            uint4 v = make_uint4(0u, 0u, 0u, 0u);
            if (j < d) {
                int c = csr[start + j];
                v = H1f8[((unsigned)c << 3) + sl];
            }
            accf8(acc, v);
        }
    }

#pragma unroll
    for (int k = 0; k < 16; ++k) {
        acc[k] += __shfl_xor(acc[k], 8);
        acc[k] += __shfl_xor(acc[k], 16);
        acc[k] += __shfl_xor(acc[k], 32);
    }

    if (g == 0) {
#pragma unroll
        for (int k = 0; k < 16; ++k) acc[k] = fmaxf(acc[k] * inv, 0.f);
        uint4 o0, o1;
        o0.x = bfpack(acc[0], acc[1]);
        o0.y = bfpack(acc[2], acc[3]);
        o0.z = bfpack(acc[4], acc[5]);
        o0.w = bfpack(acc[6], acc[7]);
        o1.x = bfpack(acc[8], acc[9]);
        o1.y = bfpack(acc[10], acc[11]);
        o1.z = bfpack(acc[12], acc[13]);
        o1.w = bfpack(acc[14], acc[15]);
        Hout[(size_t)row * 16 + sl * 2]     = o0;
        Hout[(size_t)row * 16 + sl * 2 + 1] = o1;
    }
}

// agg2: Out[row](fp32) = (1/deg) * sum h2b[c], D=64 (row = 8 uint4, bf16).
#define A2_SLOT(vv, s)                                                      \
    {                                                                       \
        int j = (s) * 8 + g;                                                \
        int c = __shfl(idx, (j < nd) ? j : 0);                              \
        vv = make_uint4(0u, 0u, 0u, 0u);                                    \
        if (j < nd) vv = H2b[((unsigned)c << 3) + sl];                      \
    }

__global__ __launch_bounds__(256) void k_agg2(const uint4* __restrict__ H2b,
                                              const int* __restrict__ offs,
                                              const int* __restrict__ degc,
                                              const float* __restrict__ invdeg,
                                              const int* __restrict__ csr,
                                              float* __restrict__ Out, int n) {
    int wave = threadIdx.x >> 6, lane = threadIdx.x & 63;
    int row = blockIdx.x * 4 + wave;
    if (row >= n) return;
    int start = offs[row], d = degc[row];
    float inv = invdeg[row];
    int g = lane >> 3;       // neighbor slot 0..7
    int sl = lane & 7;       // 16B segment within row

    int nd = d < 64 ? d : 64;
    int idx = (lane < nd) ? csr[start + lane] : 0;

    float acc[8];
#pragma unroll
    for (int k = 0; k < 8; ++k) acc[k] = 0.f;

    uint4 v0, v1;
    A2_SLOT(v0, 0) A2_SLOT(v1, 1)
    acc8(acc, v0); acc8(acc, v1);
    if (nd > 16) {
        A2_SLOT(v0, 2) A2_SLOT(v1, 3)
        acc8(acc, v0); acc8(acc, v1);
    }
    if (nd > 32) {
        A2_SLOT(v0, 4) A2_SLOT(v1, 5)
        acc8(acc, v0); acc8(acc, v1);
    }
    if (nd > 48) {
        A2_SLOT(v0, 6) A2_SLOT(v1, 7)
        acc8(acc, v0); acc8(acc, v1);
    }
    if (d > 64) {                    // rare fallback
        for (int i = 64; i < d; i += 8) {
            int j = i + g;
            uint4 v = make_uint4(0u, 0u, 0u, 0u);
            if (j < d) {
                int c = csr[start + j];
                v = H2b[((unsigned)c << 3) + sl];
            }
            acc8(acc, v);
        }
    }

#pragma unroll
    for (int k = 0; k < 8; ++k) {
        acc[k] += __shfl_xor(acc[k], 8);
        acc[k] += __shfl_xor(acc[k], 16);
        acc[k] += __shfl_xor(acc[k], 32);
    }

    if (g == 0) {
        float4 o0, o1;
        o0.x = acc[0] * inv; o0.y = acc[1] * inv;
        o0.z = acc[2] * inv; o0.w = acc[3] * inv;
        o1.x = acc[4] * inv; o1.y = acc[5] * inv;
        o1.z = acc[6] * inv; o1.w = acc[7] * inv;
        ((float4*)Out)[(size_t)row * 16 + sl * 2]     = o0;
        ((float4*)Out)[(size_t)row * 16 + sl * 2 + 1] = o1;
    }
}

extern "C" void kernel_launch(void* const* d_in, const int* in_sizes, int n_in,
                              void* d_out, int out_size, void* d_ws, size_t ws_size,
                              hipStream_t stream) {
    const float* x    = (const float*)d_in[0];
    const float* W1   = (const float*)d_in[1];
    const float* W2   = (const float*)d_in[2];
    const int*   erow = (const int*)d_in[3];
    const int*   ecol = (const int*)d_in[4];
    const int N = in_sizes[0] / DIN;
    const int E = in_sizes[3];

    const int nb  = (N + (1 << BSH) - 1) >> BSH;   // 196 buckets
    const int nch = (E + CHUNK - 1) / CHUNK;       // 391 chunks

    size_t o = 0;
    auto take = [&](size_t nbytes) {
        void* p = (char*)d_ws + o;
        o += (nbytes + 255) & ~(size_t)255;
        return p;
    };
    int*            HT     = (int*)take((size_t)nb * nch * 4);
    int*            bsum   = (int*)take((size_t)nb * 4);
    int*            bbase  = (int*)take((size_t)(nb + 1) * 4);
    int*            packed = (int*)take((size_t)E * 4);
    int*            csr    = (int*)take((size_t)E * 4);
    int*            offs   = (int*)take((size_t)N * 4);
    int*            degc   = (int*)take((size_t)N * 4);
    float*          invdeg = (float*)take((size_t)N * 4);
    unsigned short* Wt1    = (unsigned short*)take(128 * 128 * 2);
    unsigned short* Wt2    = (unsigned short*)take(64 * 128 * 2);
    unsigned char*  h1f8   = (unsigned char*)take((size_t)N * DH);  // fp8
    unsigned*       h      = (unsigned*)take((size_t)N * DH * 2);   // bf16
    unsigned*       h2b    = (unsigned*)h1f8;  // reuse (dead after agg1); 12.8MB each

    k_prep      <<<96,  256, 0, stream>>>(W1, W2, Wt1, Wt2);
    k_hist      <<<nch, 256, 0, stream>>>(erow, HT, E, nb, nch);
    k_hscan_row <<<nb,  256, 0, stream>>>(HT, bsum, nch);
    k_hscan_base<<<1,   256, 0, stream>>>(bsum, bbase, nb, E);
    k_part      <<<nch, 256, 0, stream>>>(erow, ecol, HT, bbase, packed, E, nb, nch);
    k_build     <<<nb,  256, 0, stream>>>(packed, bbase, csr, offs, degc, invdeg, N, nb);
    k_gemm1<<<(N + 63) / 64, 256, 0, stream>>>(x, Wt1, h1f8, N);
    k_agg1 <<<(N + 3) / 4, 256, 0, stream>>>((const uint4*)h1f8, offs, degc, invdeg,
                                             csr, (uint4*)h, N);
    k_gemm2<<<(N + 63) / 64, 256, 0, stream>>>(h, Wt2, (unsigned short*)h2b, N);
    k_agg2 <<<(N + 3) / 4, 256, 0, stream>>>((const uint4*)h2b, offs, degc,
                                             invdeg, csr, (float*)d_out, N);
}

// Round 7
// 265.328 us; speedup vs baseline: 1.0139x; 1.0043x over previous
//
#include <hip/hip_runtime.h>
#include <hip/hip_fp16.h>

// GraphSAGE 2-layer: logits = meanAgg(relu(meanAgg(x@W1)) @ W2)
// N=100000, E=1600000, D_IN=128, D_H=128, D_OUT=64, fp32 in/out.
//
// R2: parallel scan. R3: agg x4 unroll. R4: FAILED 1024-thr gemm (spills).
// R5: gemm W from global. R6: counting-sort CSR build (no global atomics).
// R7: bf16 gather buffers, x8 unroll. R8: parallel HT scan.
// R9: MFMA gemms; k_prep transposes W to bf16 [n][k].
// R10: wide dwordx4 gathers. R11: FAILED shfl-in-divergent-branch.
// R12: shfl hoisted wave-uniform. R13: flat unrolled gather tiers (neutral).
// R14: fp8 h1 — SLOWER despite half the bytes: agg is SIMD issue-bound;
//      fp8 unpack (24 ops/uint4) + 3-round/16-reg reduce raised inst count.
// R15: h1/h2 in fp16, packed-half accumulate: __hadd2 = 2 elems/inst ->
//      acc cost 16->4 ops per uint4, reduce regs halve. fp16 is MORE
//      precise than bf16 (absmax margin restored) and sums (<=224) are
//      far from fp16 range. gemm2 uses mfma f16; Wt2 fp16. Gather
//      geometry unchanged from R13.
// R16: resubmit of R15 (previous round died on container infra, no signal).

#define DIN 128
#define DH 128
#define DOUT 64

#define BSH 9                    // 512 rows per bucket
#define COLB 17                  // col fits 17 bits (N=100000 < 2^17)
#define COLM ((1 << COLB) - 1)
#define LRM ((1 << BSH) - 1)
#define CHUNK 4096               // edges per hist/part block
#define CH_PT 16                 // edges per thread

typedef __attribute__((ext_vector_type(8))) short short8;
typedef __attribute__((ext_vector_type(8))) _Float16 half8;
typedef __attribute__((ext_vector_type(4))) float floatx4;

__device__ __forceinline__ unsigned bfpack(float a, float b) {
    unsigned ua = __float_as_uint(a);
    unsigned ub = __float_as_uint(b);
    ua += 0x7fffu + ((ua >> 16) & 1u);
    ub += 0x7fffu + ((ub >> 16) & 1u);
    return (ua >> 16) | (ub & 0xffff0000u);
}
__device__ __forceinline__ unsigned short bf1(float a) {
    unsigned u = __float_as_uint(a);
    u += 0x7fffu + ((u >> 16) & 1u);
    return (unsigned short)(u >> 16);
}

// packed-fp16 accumulate: one uint4 = 8 fp16, 4 v_pk_add_f16
__device__ __forceinline__ void acch2(__half2* a, uint4 v) {
    a[0] = __hadd2(a[0], *(const __half2*)&v.x);
    a[1] = __hadd2(a[1], *(const __half2*)&v.y);
    a[2] = __hadd2(a[2], *(const __half2*)&v.z);
    a[3] = __hadd2(a[3], *(const __half2*)&v.w);
}
__device__ __forceinline__ __half2 h2shfl_xor(__half2 v, int m) {
    int u = __shfl_xor(*(int*)&v, m);
    return *(__half2*)&u;
}
__device__ __forceinline__ unsigned h2bits(__half2 v) {
    return *(unsigned*)&v;
}
__device__ __forceinline__ __half2 h2zero() {
    unsigned z = 0u;
    return *(__half2*)&z;
}

// ---------------- weight prep: fp32 [k][n] -> bf16/fp16 [n][k] ----------
__global__ __launch_bounds__(256) void k_prep(const float* __restrict__ W1,
                                              const float* __restrict__ W2,
                                              unsigned short* __restrict__ Wt1,
                                              unsigned short* __restrict__ Wt2) {
    int idx = blockIdx.x * 256 + threadIdx.x;
    if (idx < 128 * 128) {
        int k = idx >> 7, nn = idx & 127;
        Wt1[nn * 128 + k] = bf1(W1[idx]);          // bf16 for gemm1
    }
    int i2 = idx - 128 * 128;
    if (i2 >= 0 && i2 < 128 * 64) {
        int k = i2 >> 6, nn = i2 & 63;
        Wt2[nn * 128 + k] = __half_as_ushort(__float2half(W2[i2]));  // fp16
    }
}

// ---------------- CSR build (counting sort) ----------------

__global__ __launch_bounds__(256) void k_hist(const int* __restrict__ row,
                                              int* __restrict__ HT,
                                              int E, int nb, int nch) {
    __shared__ int h[512];
    int t = threadIdx.x, c = blockIdx.x;
    for (int i = t; i < nb; i += 256) h[i] = 0;
    __syncthreads();
    int base = c * CHUNK;
#pragma unroll
    for (int i = 0; i < CH_PT; ++i) {
        int e = base + i * 256 + t;
        if (e < E) atomicAdd(&h[row[e] >> BSH], 1);
    }
    __syncthreads();
    for (int i = t; i < nb; i += 256) HT[(size_t)i * nch + c] = h[i];
}

__global__ __launch_bounds__(256) void k_hscan_row(int* __restrict__ HT,
                                                   int* __restrict__ bsum,
                                                   int nch) {
    __shared__ int sh[256];
    int b = blockIdx.x, t = threadIdx.x;
    int carry = 0;
    for (int tile = 0; tile < nch; tile += 256) {
        int idx = tile + t;
        int v = (idx < nch) ? HT[(size_t)b * nch + idx] : 0;
        sh[t] = v;
        __syncthreads();
        for (int d = 1; d < 256; d <<= 1) {
            int u = (t >= d) ? sh[t - d] : 0;
            __syncthreads();
            sh[t] += u;
            __syncthreads();
        }
        if (idx < nch) HT[(size_t)b * nch + idx] = carry + sh[t] - v;
        carry += sh[255];
        __syncthreads();
    }
    if (t == 0) bsum[b] = carry;
}

__global__ __launch_bounds__(256) void k_hscan_base(const int* __restrict__ bsum,
                                                    int* __restrict__ bucketBase,
                                                    int nb, int E) {
    __shared__ int sh[256];
    int t = threadIdx.x;
    int v = (t < nb) ? bsum[t] : 0;
    sh[t] = v;
    __syncthreads();
    for (int d = 1; d < 256; d <<= 1) {
        int u = (t >= d) ? sh[t - d] : 0;
        __syncthreads();
        sh[t] += u;
        __syncthreads();
    }
    if (t < nb) bucketBase[t] = sh[t] - v;
    if (t == 0) bucketBase[nb] = E;
}

__global__ __launch_bounds__(256) void k_part(const int* __restrict__ row,
                                              const int* __restrict__ col,
                                              const int* __restrict__ HT,
                                              const int* __restrict__ bucketBase,
                                              int* __restrict__ packed,
                                              int E, int nb, int nch) {
    __shared__ int cur[512];
    int t = threadIdx.x, c = blockIdx.x;
    for (int i = t; i < nb; i += 256)
        cur[i] = HT[(size_t)i * nch + c] + bucketBase[i];
    __syncthreads();
    int base = c * CHUNK;
#pragma unroll
    for (int i = 0; i < CH_PT; ++i) {
        int e = base + i * 256 + t;
        if (e < E) {
            int r = row[e], cc = col[e];
            int b = r >> BSH;
            int pos = atomicAdd(&cur[b], 1);
            packed[pos] = ((r & LRM) << COLB) | cc;
        }
    }
}

__global__ __launch_bounds__(256) void k_build(const int* __restrict__ packed,
                                               const int* __restrict__ bucketBase,
                                               int* __restrict__ csr,
                                               int* __restrict__ offs,
                                               int* __restrict__ degc,
                                               float* __restrict__ invdeg,
                                               int N, int nb) {
    __shared__ int hist[512], scn[512], part[256];
    int t = threadIdx.x, b = blockIdx.x;
    int lo = bucketBase[b], hi = bucketBase[b + 1];
    int base_row = b << BSH;
    int nloc = N - base_row; if (nloc > 512) nloc = 512;
    hist[t] = 0; hist[t + 256] = 0;
    __syncthreads();
    for (int e = lo + t; e < hi; e += 256)
        atomicAdd(&hist[packed[e] >> COLB], 1);
    __syncthreads();
    int a = hist[2 * t], b2 = hist[2 * t + 1];
    part[t] = a + b2;
    __syncthreads();
    for (int d = 1; d < 256; d <<= 1) {
        int v = (t >= d) ? part[t - d] : 0;
        __syncthreads();
        part[t] += v;
        __syncthreads();
    }
    int bp = (t == 0) ? 0 : part[t - 1];
    scn[2 * t] = bp;
    scn[2 * t + 1] = bp + a;
    __syncthreads();
    for (int i = t; i < nloc; i += 256) {
        int r = base_row + i;
        offs[r] = lo + scn[i];
        int d = hist[i];
        degc[r] = d;
        invdeg[r] = 1.0f / (float)d;
    }
    __syncthreads();
    for (int e = lo + t; e < hi; e += 256) {
        int p = packed[e];
        int pos = lo + atomicAdd(&scn[p >> COLB], 1);
        csr[pos] = p & COLM;
    }
}

// ---------------- MFMA GEMMs ----------------

// h1h[n,128](fp16) = X @ W1 (bf16 MFMA, fp16 store). 64-row block.
__global__ __launch_bounds__(256) void k_gemm1(const float* __restrict__ X,
                                               const unsigned short* __restrict__ Wt,
                                               unsigned short* __restrict__ H1h, int n) {
    __shared__ unsigned short xs[64][136];    // pitch 272B: 2-way-bank-safe b128
    __shared__ unsigned short wt[128][136];
    int tid = threadIdx.x;
    int r0 = blockIdx.x * 64;

    for (int i = tid; i < 64 * 32; i += 256) {
        int r = i >> 5, c4 = i & 31;
        float4 v = make_float4(0.f, 0.f, 0.f, 0.f);
        if (r0 + r < n) v = ((const float4*)X)[(size_t)(r0 + r) * 32 + c4];
        *(uint2*)&xs[r][c4 * 4] = make_uint2(bfpack(v.x, v.y), bfpack(v.z, v.w));
    }
    for (int i = tid; i < 128 * 16; i += 256) {
        int r = i >> 4, c = i & 15;
        *(uint4*)&wt[r][c * 8] = ((const uint4*)Wt)[r * 16 + c];
    }
    __syncthreads();

    int w = tid >> 6, lane = tid & 63;
    int ml = lane & 15, q = lane >> 4;
    floatx4 acc[8];
#pragma unroll
    for (int t = 0; t < 8; ++t) acc[t] = (floatx4)(0.f);

#pragma unroll
    for (int kc = 0; kc < 4; ++kc) {
        short8 af = *(const short8*)&xs[w * 16 + ml][kc * 32 + q * 8];
#pragma unroll
        for (int nt = 0; nt < 8; ++nt) {
            short8 bf = *(const short8*)&wt[nt * 16 + ml][kc * 32 + q * 8];
            acc[nt] = __builtin_amdgcn_mfma_f32_16x16x32_bf16(af, bf, acc[nt], 0, 0, 0);
        }
    }
#pragma unroll
    for (int nt = 0; nt < 8; ++nt)
#pragma unroll
        for (int r = 0; r < 4; ++r) {
            int rr = r0 + w * 16 + q * 4 + r;
            if (rr < n)
                H1h[(size_t)rr * 128 + nt * 16 + ml] =
                    __half_as_ushort(__float2half(acc[nt][r]));
        }
}

// h2h[n,64](fp16) = h(fp16) @ W2 (f16 MFMA). Same structure, N=64.
__global__ __launch_bounds__(256) void k_gemm2(const unsigned* __restrict__ Hin,
                                               const unsigned short* __restrict__ Wt,
                                               unsigned short* __restrict__ H2h, int n) {
    __shared__ unsigned short xs[64][136];
    __shared__ unsigned short wt[64][136];
    int tid = threadIdx.x;
    int r0 = blockIdx.x * 64;

    for (int i = tid; i < 64 * 16; i += 256) {
        int r = i >> 4, c = i & 15;
        uint4 v = make_uint4(0u, 0u, 0u, 0u);
        if (r0 + r < n) v = ((const uint4*)Hin)[(size_t)(r0 + r) * 16 + c];
        *(uint4*)&xs[r][c * 8] = v;
    }
    for (int i = tid; i < 64 * 16; i += 256) {
        int r = i >> 4, c = i & 15;
        *(uint4*)&wt[r][c * 8] = ((const uint4*)Wt)[r * 16 + c];
    }
    __syncthreads();

    int w = tid >> 6, lane = tid & 63;
    int ml = lane & 15, q = lane >> 4;
    floatx4 acc[4];
#pragma unroll
    for (int t = 0; t < 4; ++t) acc[t] = (floatx4)(0.f);

#pragma unroll
    for (int kc = 0; kc < 4; ++kc) {
        half8 af = *(const half8*)&xs[w * 16 + ml][kc * 32 + q * 8];
#pragma unroll
        for (int nt = 0; nt < 4; ++nt) {
            half8 bf = *(const half8*)&wt[nt * 16 + ml][kc * 32 + q * 8];
            acc[nt] = __builtin_amdgcn_mfma_f32_16x16x32_f16(af, bf, acc[nt], 0, 0, 0);
        }
    }
#pragma unroll
    for (int nt = 0; nt < 4; ++nt)
#pragma unroll
        for (int r = 0; r < 4; ++r) {
            int rr = r0 + w * 16 + q * 4 + r;
            if (rr < n)
                H2h[(size_t)rr * 64 + nt * 16 + ml] =
                    __half_as_ushort(__float2half(acc[nt][r]));
        }
}

// ---------------- Aggregations ----------------

// agg1: h[row](fp16) = relu((1/deg) * sum h1h[c]), D=128 (row = 16 uint4).
// csr row cached in regs, wave-uniform shfl distribution, unrolled tiers
// (R13). Packed-fp16 accumulate (__hadd2, 4 inst/uint4) -> 4 half2 acc
// regs; reduce is 2 rounds x 4 regs. Epilogue (g==0) converts to f32,
// scales, relu, repacks fp16.
#define A1_SLOT(vv, s)                                                      \
    {                                                                       \
        int j = (s) * 4 + g;                                                \
        int c = __shfl(idx, (j < nd) ? j : 0);                              \
        vv = make_uint4(0u, 0u, 0u, 0u);                                    \
        if (j < nd) vv = H1h[((unsigned)c << 4) + sl];                      \
    }

__global__ __launch_bounds__(256) void k_agg1(const uint4* __restrict__ H1h,
                                              const int* __restrict__ offs,
                                              const int* __restrict__ degc,
                                              const float* __restrict__ invdeg,
                                              const int* __restrict__ csr,
                                              uint4* __restrict__ Hout, int n) {
    int wave = threadIdx.x >> 6, lane = threadIdx.x & 63;
    int row = blockIdx.x * 4 + wave;
    if (row >= n) return;
    int start = offs[row], d = degc[row];
    float inv = invdeg[row];
    int g = lane >> 4;       // neighbor slot 0..3
    int sl = lane & 15;      // 16B segment within 256B fp16 row

    int nd = d < 64 ? d : 64;
    int idx = (lane < nd) ? csr[start + lane] : 0;

    __half2 acc[4];
#pragma unroll
    for (int k = 0; k < 4; ++k) acc[k] = h2zero();

    uint4 v0, v1, v2, v3;
    A1_SLOT(v0, 0) A1_SLOT(v1, 1) A1_SLOT(v2, 2) A1_SLOT(v3, 3)
    acch2(acc, v0); acch2(acc, v1); acch2(acc, v2); acch2(acc, v3);
    if (nd > 16) {
        A1_SLOT(v0, 4) A1_SLOT(v1, 5) A1_SLOT(v2, 6) A1_SLOT(v3, 7)
        acch2(acc, v0); acch2(acc, v1); acch2(acc, v2); acch2(acc, v3);
    }
    if (nd > 32) {
        A1_SLOT(v0, 8) A1_SLOT(v1, 9) A1_SLOT(v2, 10) A1_SLOT(v3, 11)
        acch2(acc, v0); acch2(acc, v1); acch2(acc, v2); acch2(acc, v3);
    }
    if (nd > 48) {
        A1_SLOT(v0, 12) A1_SLOT(v1, 13) A1_SLOT(v2, 14) A1_SLOT(v3, 15)
        acch2(acc, v0); acch2(acc, v1); acch2(acc, v2); acch2(acc, v3);
    }
    if (d > 64) {                    // rare fallback
        for (int i = 64; i < d; i += 4) {
            int j = i + g;
            uint4 v = make_uint4(0u, 0u, 0u, 0u);
            if (j < d) {
                int c = csr[start + j];
                v = H1h[((unsigned)c << 4) + sl];
            }
            acch2(acc, v);
        }
    }

#pragma unroll
    for (int k = 0; k < 4; ++k) {
        acc[k] = __hadd2(acc[k], h2shfl_xor(acc[k], 16));
        acc[k] = __hadd2(acc[k], h2shfl_xor(acc[k], 32));
    }

    if (g == 0) {
        float f[8];
#pragma unroll
        for (int k = 0; k < 4; ++k) {
            f[2 * k]     = fmaxf(__low2float(acc[k]) * inv, 0.f);
            f[2 * k + 1] = fmaxf(__high2float(acc[k]) * inv, 0.f);
        }
        uint4 o;
        __half2 t0 = __floats2half2_rn(f[0], f[1]);
        __half2 t1 = __floats2half2_rn(f[2], f[3]);
        __half2 t2 = __floats2half2_rn(f[4], f[5]);
        __half2 t3 = __floats2half2_rn(f[6], f[7]);
        o.x = h2bits(t0); o.y = h2bits(t1); o.z = h2bits(t2); o.w = h2bits(t3);
        Hout[(size_t)row * 16 + sl] = o;
    }
}

// agg2: Out[row](fp32) = (1/deg) * sum h2h[c], D=64 (row = 8 uint4, fp16).
// 8-lane groups, packed-fp16 accumulate, 3-round reduce on 4 regs.
#define A2_SLOT(vv, s)                                                      \
    {                                                                       \
        int j = (s) * 8 + g;                                                \
        int c = __shfl(idx, (j < nd) ? j : 0);                              \
        vv = make_uint4(0u, 0u, 0u, 0u);                                    \
        if (j < nd) vv = H2h[((unsigned)c << 3) + sl];                      \
    }

__global__ __launch_bounds__(256) void k_agg2(const uint4* __restrict__ H2h,
                                              const int* __restrict__ offs,
                                              const int* __restrict__ degc,
                                              const float* __restrict__ invdeg,
                                              const int* __restrict__ csr,
                                              float* __restrict__ Out, int n) {
    int wave = threadIdx.x >> 6, lane = threadIdx.x & 63;
    int row = blockIdx.x * 4 + wave;
    if (row >= n) return;
    int start = offs[row], d = degc[row];
    float inv = invdeg[row];
    int g = lane >> 3;       // neighbor slot 0..7
    int sl = lane & 7;       // 16B segment within 128B fp16 row

    int nd = d < 64 ? d : 64;
    int idx = (lane < nd) ? csr[start + lane] : 0;

    __half2 acc[4];
#pragma unroll
    for (int k = 0; k < 4; ++k) acc[k] = h2zero();

    uint4 v0, v1;
    A2_SLOT(v0, 0) A2_SLOT(v1, 1)
    acch2(acc, v0); acch2(acc, v1);
    if (nd > 16) {
        A2_SLOT(v0, 2) A2_SLOT(v1, 3)
        acch2(acc, v0); acch2(acc, v1);
    }
    if (nd > 32) {
        A2_SLOT(v0, 4) A2_SLOT(v1, 5)
        acch2(acc, v0); acch2(acc, v1);
    }
    if (nd > 48) {
        A2_SLOT(v0, 6) A2_SLOT(v1, 7)
        acch2(acc, v0); acch2(acc, v1);
    }
    if (d > 64) {                    // rare fallback
        for (int i = 64; i < d; i += 8) {
            int j = i + g;
            uint4 v = make_uint4(0u, 0u, 0u, 0u);
            if (j < d) {
                int c = csr[start + j];
                v = H2h[((unsigned)c << 3) + sl];
            }
            acch2(acc, v);
        }
    }

#pragma unroll
    for (int k = 0; k < 4; ++k) {
        acc[k] = __hadd2(acc[k], h2shfl_xor(acc[k], 8));
        acc[k] = __hadd2(acc[k], h2shfl_xor(acc[k], 16));
        acc[k] = __hadd2(acc[k], h2shfl_xor(acc[k], 32));
    }

    if (g == 0) {
        float4 o0, o1;
        o0.x = __low2float(acc[0]) * inv;  o0.y = __high2float(acc[0]) * inv;
        o0.z = __low2float(acc[1]) * inv;  o0.w = __high2float(acc[1]) * inv;
        o1.x = __low2float(acc[2]) * inv;  o1.y = __high2float(acc[2]) * inv;
        o1.z = __low2float(acc[3]) * inv;  o1.w = __high2float(acc[3]) * inv;
        ((float4*)Out)[(size_t)row * 16 + sl * 2]     = o0;
        ((float4*)Out)[(size_t)row * 16 + sl * 2 + 1] = o1;
    }
}

extern "C" void kernel_launch(void* const* d_in, const int* in_sizes, int n_in,
                              void* d_out, int out_size, void* d_ws, size_t ws_size,
                              hipStream_t stream) {
    const float* x    = (const float*)d_in[0];
    const float* W1   = (const float*)d_in[1];
    const float* W2   = (const float*)d_in[2];
    const int*   erow = (const int*)d_in[3];
    const int*   ecol = (const int*)d_in[4];
    const int N = in_sizes[0] / DIN;
    const int E = in_sizes[3];

    const int nb  = (N + (1 << BSH) - 1) >> BSH;   // 196 buckets
    const int nch = (E + CHUNK - 1) / CHUNK;       // 391 chunks

    size_t o = 0;
    auto take = [&](size_t nbytes) {
        void* p = (char*)d_ws + o;
        o += (nbytes + 255) & ~(size_t)255;
        return p;
    };
    int*            HT     = (int*)take((size_t)nb * nch * 4);
    int*            bsum   = (int*)take((size_t)nb * 4);
    int*            bbase  = (int*)take((size_t)(nb + 1) * 4);
    int*            packed = (int*)take((size_t)E * 4);
    int*            csr    = (int*)take((size_t)E * 4);
    int*            offs   = (int*)take((size_t)N * 4);
    int*            degc   = (int*)take((size_t)N * 4);
    float*          invdeg = (float*)take((size_t)N * 4);
    unsigned short* Wt1    = (unsigned short*)take(128 * 128 * 2);
    unsigned short* Wt2    = (unsigned short*)take(64 * 128 * 2);
    unsigned short* h1h    = (unsigned short*)take((size_t)N * DH * 2);  // fp16
    unsigned*       h      = (unsigned*)take((size_t)N * DH * 2);        // fp16
    unsigned short* h2h    = h1h;   // reuse (dead after agg1); 12.8MB needed

    k_prep      <<<96,  256, 0, stream>>>(W1, W2, Wt1, Wt2);
    k_hist      <<<nch, 256, 0, stream>>>(erow, HT, E, nb, nch);
    k_hscan_row <<<nb,  256, 0, stream>>>(HT, bsum, nch);
    k_hscan_base<<<1,   256, 0, stream>>>(bsum, bbase, nb, E);
    k_part      <<<nch, 256, 0, stream>>>(erow, ecol, HT, bbase, packed, E, nb, nch);
    k_build     <<<nb,  256, 0, stream>>>(packed, bbase, csr, offs, degc, invdeg, N, nb);
    k_gemm1<<<(N + 63) / 64, 256, 0, stream>>>(x, Wt1, h1h, N);
    k_agg1 <<<(N + 3) / 4, 256, 0, stream>>>((const uint4*)h1h, offs, degc, invdeg,
                                             csr, (uint4*)h, N);
    k_gemm2<<<(N + 63) / 64, 256, 0, stream>>>(h, Wt2, h2h, N);
    k_agg2 <<<(N + 3) / 4, 256, 0, stream>>>((const uint4*)h2h, offs, degc,
                                             invdeg, csr, (float*)d_out, N);
}